// Round 8
// baseline (457.016 us; speedup 1.0000x reference)
//
#include <hip/hip_runtime.h>
#include <cstdint>

// Per-pixel channel permutation, image (C=16, W=2048, H=2048) f32.
// out[k,i,j] = image[perm[i,j,k], i, j], perm = stable argsort over channels of
// jax.random.uniform(key(1), (W,H,C)) with threefry_partitionable=True:
//   bits[i] = x0 ^ x1 of threefry2x32(key=(0,1), ctr=(0, i)), i = 16*pixel + k
//   float order == order of (bits >> 9)
//
// R5 -> R6 (VALU-bound, VALUBusy 83%): trim non-RNG VALU + fix tail serialization.
//  - key pack: ((bits>>5) & 0x7FFFFF0) | k  -> lshr + and_or (2 ops, was 3)
//  - tail: batch all 16 ds_reads into regs, then 16 back-to-back stores
//    (one lgkm drain instead of 16 interleaved ds_read/store waits)
//  - threefry advanced as 2 independent lockstep chains (explicit ILP)

#define NPIX 4194304u  // 2048*2048

__device__ __forceinline__ uint32_t rotl(uint32_t x, int r) {
  return __builtin_amdgcn_alignbit(x, x, 32 - r);  // 1x v_alignbit_b32
}

// Two independent threefry2x32 evals (key=(0,1), ctr=(0, c1a/c1b)) in lockstep.
__device__ __forceinline__ void tf_bits2(uint32_t c1a, uint32_t c1b,
                                         uint32_t& outa, uint32_t& outb) {
  const uint32_t KS2 = 0x1BD11BDBu;  // 0 ^ 1 ^ 0x1BD11BDA
  uint32_t a0 = 0u, a1 = c1a + 1u;
  uint32_t b0 = 0u, b1 = c1b + 1u;
#define TF_RND(r) { a0 += a1; b0 += b1; a1 = rotl(a1, r); b1 = rotl(b1, r); \
                    a1 ^= a0; b1 ^= b0; }
  TF_RND(13) TF_RND(15) TF_RND(26) TF_RND(6)
  a0 += 1u;  b0 += 1u;  a1 += KS2 + 1u;  b1 += KS2 + 1u;   // ks[1], ks[2]+1
  TF_RND(17) TF_RND(29) TF_RND(16) TF_RND(24)
  a0 += KS2; b0 += KS2; a1 += 2u;        b1 += 2u;         // ks[2], ks[0]+2
  TF_RND(13) TF_RND(15) TF_RND(26) TF_RND(6)
  a1 += 4u;  b1 += 4u;                                     // ks[0], ks[1]+3
  TF_RND(17) TF_RND(29) TF_RND(16) TF_RND(24)
  a0 += 1u;  b0 += 1u;  a1 += KS2 + 4u;  b1 += KS2 + 4u;   // ks[1], ks[2]+4
  TF_RND(13) TF_RND(15) TF_RND(26) TF_RND(6)
  a0 += KS2; b0 += KS2; a1 += 5u;        b1 += 5u;         // ks[2], ks[0]+5
#undef TF_RND
  outa = a0 ^ a1;
  outb = b0 ^ b1;
}

__global__ __launch_bounds__(256) void
ppcp_kernel(const float* __restrict__ img, float* __restrict__ out) {
  __shared__ float buf[16][256];  // 16 KB; column tid is private to its wave
  const uint32_t tid = threadIdx.x;
  const uint32_t wbase = tid & 192u;               // wave id * 64
  const uint32_t p = blockIdx.x * 256u + tid;      // pixel index [0, NPIX)

  // Stage all 16 channel values straight into LDS (async, no VGPR roundtrip).
#pragma unroll
  for (int k = 0; k < 16; ++k) {
    __builtin_amdgcn_global_load_lds(
        (const __attribute__((address_space(1))) uint32_t*)(img + (size_t)k * NPIX + p),
        (__attribute__((address_space(3))) uint32_t*)&buf[k][wbase],
        4, 0, 0);
  }

  // Packed sort keys: ((bits>>9) << 4) | k == ((bits>>5) & 0x7FFFFF0) | k.
  // Distinct by construction => min/max network is stable-argsort-exact.
  const uint32_t cbase = p * 16u;
  uint32_t key[16];
#pragma unroll
  for (int k = 0; k < 16; k += 2) {
    uint32_t ba, bb;
    tf_bits2(cbase + (uint32_t)k, cbase + (uint32_t)(k + 1), ba, bb);
    key[k]     = ((ba >> 5) & 0x7FFFFF0u) | (uint32_t)k;
    key[k + 1] = ((bb >> 5) & 0x7FFFFF0u) | (uint32_t)(k + 1);
  }

  // Batcher odd-even mergesort, n=16: 63 compare-exchanges, min/max only.
#pragma unroll
  for (int pp = 1; pp < 16; pp <<= 1) {
#pragma unroll
    for (int kk = pp; kk >= 1; kk >>= 1) {
#pragma unroll
      for (int j = kk % pp; j + kk < 16; j += 2 * kk) {
#pragma unroll
        for (int i = 0; i < kk; ++i) {
          if (i + j + kk < 16 && (i + j) / (2 * pp) == (i + j + kk) / (2 * pp)) {
            const int a = i + j, b = i + j + kk;
            const uint32_t lo = min(key[a], key[b]);
            const uint32_t hi = max(key[a], key[b]);
            key[a] = lo; key[b] = hi;
          }
        }
      }
    }
  }

  // Wait for staged values; batch-gather to regs, then back-to-back stores.
  // buf[src][tid]: bank = tid & 31 independent of src -> 2 lanes/bank, free.
  asm volatile("s_waitcnt vmcnt(0)" ::: "memory");
  float vv[16];
#pragma unroll
  for (int r = 0; r < 16; ++r)
    vv[r] = buf[key[r] & 15u][tid];   // argsort[r] = source channel for rank r
  float* op = out + p;
#pragma unroll
  for (int r = 0; r < 16; ++r)
    op[(size_t)r * NPIX] = vv[r];
}

extern "C" void kernel_launch(void* const* d_in, const int* in_sizes, int n_in,
                              void* d_out, int out_size, void* d_ws, size_t ws_size,
                              hipStream_t stream) {
  const float* img = (const float*)d_in[0];
  float* out = (float*)d_out;
  ppcp_kernel<<<dim3(NPIX / 256u), dim3(256), 0, stream>>>(img, out);
}